// Round 1
// baseline (480.882 us; speedup 1.0000x reference)
//
#include <hip/hip_runtime.h>
#include <hip/hip_bf16.h>
#include <math.h>

#define NN 50000
#define NE 800000

// ---------------------------------------------------------------------------
// init: zero deg/cursor; detect edge dtype (int64 vs int32) into flag
// ---------------------------------------------------------------------------
__global__ void k_init(int* flag, int* deg, int* cursor, const void* edges) {
    int i = blockIdx.x * 256 + threadIdx.x;
    if (i < NN) { deg[i] = 0; cursor[i] = 0; }
    if (blockIdx.x == 0 && threadIdx.x < 64) {
        // If data is really int64, all values are in [0, NN). If it is int32,
        // an int64 view combines pairs -> huge values (any nonzero odd elem).
        const long long* q = (const long long*)edges;
        long long v = q[threadIdx.x];
        int ok = (v >= 0 && v < NN) ? 1 : 0;
        unsigned long long m = __ballot(ok);
        if (threadIdx.x == 0) *flag = (m == ~0ull) ? 1 : 0;
    }
}

__device__ inline int edge_at(const void* edges, int is64, int i) {
    return is64 ? (int)((const long long*)edges)[i] : ((const int*)edges)[i];
}

// ---------------------------------------------------------------------------
// histogram of dst
// ---------------------------------------------------------------------------
__global__ void k_hist(const void* edges, const int* flag, int* deg) {
    int e = blockIdx.x * 256 + threadIdx.x;
    if (e >= NE) return;
    int is64 = *flag;
    int dst = edge_at(edges, is64, NE + e);
    atomicAdd(&deg[dst], 1);
}

// ---------------------------------------------------------------------------
// exclusive scan of deg -> offs  (single block, 1024 threads, shuffle scan)
// ---------------------------------------------------------------------------
__global__ void k_scan(const int* deg, int* offs) {
    __shared__ int wsum[16];
    int tid = threadIdx.x, lane = tid & 63, w = tid >> 6;
    int base = 0;
    for (int start = 0; start < NN; start += 1024) {
        int i = start + tid;
        int v = (i < NN) ? deg[i] : 0;
        int orig = v;
        #pragma unroll
        for (int d = 1; d < 64; d <<= 1) { int t = __shfl_up(v, d); if (lane >= d) v += t; }
        if (lane == 63) wsum[w] = v;
        __syncthreads();
        if (w == 0 && lane < 16) {
            int s = wsum[lane];
            #pragma unroll
            for (int d = 1; d < 16; d <<= 1) { int t = __shfl_up(s, d); if (lane >= d) s += t; }
            wsum[lane] = s;
        }
        __syncthreads();
        int wpre = (w == 0) ? 0 : wsum[w - 1];
        int total = wsum[15];
        if (i < NN) offs[i] = base + wpre + (v - orig);
        base += total;
        __syncthreads();
    }
    if (tid == 0) offs[NN] = base;
}

// ---------------------------------------------------------------------------
// scatter edges into dst-sorted order
// ---------------------------------------------------------------------------
__global__ void k_scatter(const void* edges, const int* flag, const int* offs,
                          int* cursor, int* ssrc) {
    int e = blockIdx.x * 256 + threadIdx.x;
    if (e >= NE) return;
    int is64 = *flag;
    int s = edge_at(edges, is64, e);
    int dst = edge_at(edges, is64, NE + e);
    int pos = atomicAdd(&cursor[dst], 1);
    ssrc[offs[dst] + pos] = s;
}

// ---------------------------------------------------------------------------
// mean-aggregate 128-channel features: one wave per node
// feat row-stride 128, out row-stride 128
// ---------------------------------------------------------------------------
__global__ void k_agg(const float* __restrict__ feat, const int* __restrict__ offs,
                      const int* __restrict__ ssrc, float* __restrict__ aggout) {
    int node = blockIdx.x * 4 + (threadIdx.x >> 6);
    int lane = threadIdx.x & 63;
    if (node >= NN) return;
    int s0 = offs[node], s1 = offs[node + 1];
    float a0 = 0.f, a1 = 0.f;
    for (int e = s0; e < s1; ++e) {
        int s = ssrc[e];
        const float* row = feat + (size_t)s * 128;
        a0 += row[lane];
        a1 += row[lane + 64];
    }
    float inv = 1.0f / fmaxf((float)(s1 - s0), 1.0f);
    aggout[(size_t)node * 128 + lane] = a0 * inv;
    aggout[(size_t)node * 128 + lane + 64] = a1 * inv;
}

// ---------------------------------------------------------------------------
// fp32 GEMM, M=50000, N=256, K=256, 64x64 tile, 4x4 microtile.
// MODE 1: A=[agg1|x] (row-stride 128 each), B=[W1l;W1r] stacked on K,
//         C = relu(acc + b1) -> h (stride 256)
// MODE 2: A=h (stride 256), B=[W2l|W2r] split on N (each 256x128),
//         C = acc -> pr (stride 256)
// ---------------------------------------------------------------------------
template <int MODE>
__global__ __launch_bounds__(256)
void k_gemm(const float* __restrict__ A0, const float* __restrict__ A1,
            const float* __restrict__ B0, const float* __restrict__ B1,
            const float* __restrict__ bias, float* __restrict__ C) {
    __shared__ float As[32][68];   // [k][m], stride 68 floats = 272B (16B mult)
    __shared__ float Bs[32][64];   // [k][n]
    int t = threadIdx.x;
    int m0 = blockIdx.x * 64;
    int n0 = blockIdx.y * 64;
    int tm = t >> 4, tn = t & 15;
    float acc[4][4] = {};

    for (int k0 = 0; k0 < 256; k0 += 32) {
        // ---- A tile -> As[k][m] (transposed store)
        {
            int f0 = t * 2;
            #pragma unroll
            for (int q = 0; q < 2; ++q) {
                int f = f0 + q;
                int ml = f >> 3, kl = (f & 7) * 4;
                int m = m0 + ml;
                float4 v = make_float4(0.f, 0.f, 0.f, 0.f);
                if (m < NN) {
                    const float* src;
                    if (MODE == 1) {
                        int k = k0 + kl;
                        src = (k < 128) ? (A0 + (size_t)m * 128 + k)
                                        : (A1 + (size_t)m * 128 + (k - 128));
                    } else {
                        src = A0 + (size_t)m * 256 + k0 + kl;
                    }
                    v = *(const float4*)src;
                }
                As[kl + 0][ml] = v.x;
                As[kl + 1][ml] = v.y;
                As[kl + 2][ml] = v.z;
                As[kl + 3][ml] = v.w;
            }
        }
        // ---- B tile -> Bs[k][n]
        {
            #pragma unroll
            for (int q = 0; q < 2; ++q) {
                int f = t + 256 * q;
                int kl = f >> 4, c4 = (f & 15) * 4;
                int k = k0 + kl;
                const float* src;
                if (MODE == 1) {
                    src = (k < 128) ? (B0 + (size_t)k * 256 + n0 + c4)
                                    : (B1 + (size_t)(k - 128) * 256 + n0 + c4);
                } else {
                    int n = n0 + c4;
                    src = (n < 128) ? (B0 + (size_t)k * 128 + n)
                                    : (B1 + (size_t)k * 128 + (n - 128));
                }
                *(float4*)&Bs[kl][c4] = *(const float4*)src;
            }
        }
        __syncthreads();
        #pragma unroll
        for (int kk = 0; kk < 32; ++kk) {
            float4 a = *(const float4*)&As[kk][tm * 4];
            float4 b = *(const float4*)&Bs[kk][tn * 4];
            float av[4] = {a.x, a.y, a.z, a.w};
            float bv[4] = {b.x, b.y, b.z, b.w};
            #pragma unroll
            for (int i = 0; i < 4; ++i)
                #pragma unroll
                for (int j = 0; j < 4; ++j)
                    acc[i][j] += av[i] * bv[j];
        }
        __syncthreads();
    }

    // ---- epilogue
    #pragma unroll
    for (int i = 0; i < 4; ++i) {
        int m = m0 + tm * 4 + i;
        if (m >= NN) continue;
        int n = n0 + tn * 4;
        float4 r = make_float4(acc[i][0], acc[i][1], acc[i][2], acc[i][3]);
        if (MODE == 1) {
            const float4 bb = *(const float4*)&bias[n];
            r.x = fmaxf(r.x + bb.x, 0.f);
            r.y = fmaxf(r.y + bb.y, 0.f);
            r.z = fmaxf(r.z + bb.z, 0.f);
            r.w = fmaxf(r.w + bb.w, 0.f);
        }
        *(float4*)&C[(size_t)m * 256 + n] = r;
    }
}

// ---------------------------------------------------------------------------
// final: out = log_softmax( mean_agg(p)[i] + r[i] + b2 ), p=pr[:, :128],
// r=pr[:,128:]. One wave per node; 2 channels per lane.
// ---------------------------------------------------------------------------
__global__ void k_final(const float* __restrict__ pr, const int* __restrict__ offs,
                        const int* __restrict__ ssrc, const float* __restrict__ b2,
                        float* __restrict__ out) {
    int node = blockIdx.x * 4 + (threadIdx.x >> 6);
    int lane = threadIdx.x & 63;
    if (node >= NN) return;
    int s0 = offs[node], s1 = offs[node + 1];
    float a0 = 0.f, a1 = 0.f;
    for (int e = s0; e < s1; ++e) {
        int s = ssrc[e];
        const float* row = pr + (size_t)s * 256;
        a0 += row[lane];
        a1 += row[lane + 64];
    }
    float inv = 1.0f / fmaxf((float)(s1 - s0), 1.0f);
    const float* myrow = pr + (size_t)node * 256;
    float v0 = a0 * inv + myrow[128 + lane] + b2[lane];
    float v1 = a1 * inv + myrow[192 + lane] + b2[lane + 64];

    float mx = fmaxf(v0, v1);
    #pragma unroll
    for (int d = 1; d < 64; d <<= 1) mx = fmaxf(mx, __shfl_xor(mx, d));
    float s = __expf(v0 - mx) + __expf(v1 - mx);
    #pragma unroll
    for (int d = 1; d < 64; d <<= 1) s += __shfl_xor(s, d);
    float ls = __logf(s);
    out[(size_t)node * 128 + lane] = v0 - mx - ls;
    out[(size_t)node * 128 + lane + 64] = v1 - mx - ls;
}

// ---------------------------------------------------------------------------
extern "C" void kernel_launch(void* const* d_in, const int* in_sizes, int n_in,
                              void* d_out, int out_size, void* d_ws, size_t ws_size,
                              hipStream_t stream) {
    const float* x   = (const float*)d_in[0];
    const void*  edg = d_in[1];
    const float* W1l = (const float*)d_in[2];
    const float* W1r = (const float*)d_in[3];
    const float* b1  = (const float*)d_in[4];
    const float* W2l = (const float*)d_in[5];
    const float* W2r = (const float*)d_in[6];
    const float* b2  = (const float*)d_in[7];
    float* out = (float*)d_out;

    char* ws = (char*)d_ws;
    size_t off = 0;
    auto alloc = [&](size_t bytes) {
        size_t cur = off;
        off = (off + bytes + 255) & ~(size_t)255;
        return cur;
    };
    int*   flag   = (int*)(ws + alloc(4));
    int*   deg    = (int*)(ws + alloc((size_t)NN * 4));
    int*   offs   = (int*)(ws + alloc((size_t)(NN + 1) * 4));
    int*   cursor = (int*)(ws + alloc((size_t)NN * 4));
    int*   ssrc   = (int*)(ws + alloc((size_t)NE * 4));
    float* bufA   = (float*)(ws + alloc((size_t)NN * 256 * 4)); // agg1 then pr
    float* bufH   = (float*)(ws + alloc((size_t)NN * 256 * 4)); // h

    int nb_n = (NN + 255) / 256;
    int nb_e = (NE + 255) / 256;
    int nb_w = (NN + 3) / 4;       // 4 waves (nodes) per 256-thread block
    int mblocks = (NN + 63) / 64;  // 782

    k_init<<<nb_n, 256, 0, stream>>>(flag, deg, cursor, edg);
    k_hist<<<nb_e, 256, 0, stream>>>(edg, flag, deg);
    k_scan<<<1, 1024, 0, stream>>>(deg, offs);
    k_scatter<<<nb_e, 256, 0, stream>>>(edg, flag, offs, cursor, ssrc);
    // layer 1: agg1 = mean-agg(x)   [NN,128] -> bufA
    k_agg<<<nb_w, 256, 0, stream>>>(x, offs, ssrc, bufA);
    // h = relu([agg1|x] @ [W1l;W1r] + b1)   -> bufH [NN,256]
    k_gemm<1><<<dim3(mblocks, 4), 256, 0, stream>>>(bufA, x, W1l, W1r, b1, bufH);
    // pr = h @ [W2l|W2r]  -> bufA [NN,256]  (p = cols 0:128, r = cols 128:256)
    k_gemm<2><<<dim3(mblocks, 4), 256, 0, stream>>>(bufH, nullptr, W2l, W2r, nullptr, bufA);
    // out = log_softmax(mean-agg(p) + r + b2)
    k_final<<<nb_w, 256, 0, stream>>>(bufA, offs, ssrc, b2, out);
}

// Round 2
// 320.970 us; speedup vs baseline: 1.4982x; 1.4982x over previous
//
#include <hip/hip_runtime.h>
#include <math.h>

#define NN 50000
#define NE 800000

typedef __attribute__((ext_vector_type(8))) short short8;
typedef __attribute__((ext_vector_type(4))) float f32x4;
typedef unsigned int uint32;

__device__ inline unsigned short f2bf(float f) {
    unsigned u = __builtin_bit_cast(unsigned, f);
    u += 0x7FFF + ((u >> 16) & 1);   // RNE
    return (unsigned short)(u >> 16);
}

// ---------------------------------------------------------------------------
// init: zero deg/cursor; detect edge dtype (int64 vs int32) into flag
// ---------------------------------------------------------------------------
__global__ void k_init(int* flag, int* deg, int* cursor, const void* edges) {
    int i = blockIdx.x * 256 + threadIdx.x;
    if (i < NN) { deg[i] = 0; cursor[i] = 0; }
    if (blockIdx.x == 0 && threadIdx.x < 64) {
        const long long* q = (const long long*)edges;
        long long v = q[threadIdx.x];
        int ok = (v >= 0 && v < NN) ? 1 : 0;
        unsigned long long m = __ballot(ok);
        if (threadIdx.x == 0) *flag = (m == ~0ull) ? 1 : 0;
    }
}

__device__ inline int edge_at(const void* edges, int is64, int i) {
    return is64 ? (int)((const long long*)edges)[i] : ((const int*)edges)[i];
}

__global__ void k_hist(const void* edges, const int* flag, int* deg) {
    int e = blockIdx.x * 256 + threadIdx.x;
    if (e >= NE) return;
    int is64 = *flag;
    int dst = edge_at(edges, is64, NE + e);
    atomicAdd(&deg[dst], 1);
}

// exclusive scan of deg -> offs (single block, 1024 thr, 4 elems/thread)
__global__ void k_scan(const int* deg, int* offs) {
    __shared__ int wsum[16];
    int tid = threadIdx.x, lane = tid & 63, w = tid >> 6;
    int base = 0;
    for (int start = 0; start < NN; start += 4096) {
        int i0 = start + tid * 4;
        int d0 = 0, d1 = 0, d2 = 0, d3 = 0;
        if (i0 + 3 < NN) {
            int4 q = *(const int4*)(deg + i0);
            d0 = q.x; d1 = q.y; d2 = q.z; d3 = q.w;
        } else {
            if (i0 + 0 < NN) d0 = deg[i0 + 0];
            if (i0 + 1 < NN) d1 = deg[i0 + 1];
            if (i0 + 2 < NN) d2 = deg[i0 + 2];
            if (i0 + 3 < NN) d3 = deg[i0 + 3];
        }
        int tsum = d0 + d1 + d2 + d3;
        int v = tsum;
        #pragma unroll
        for (int d = 1; d < 64; d <<= 1) { int t = __shfl_up(v, d); if (lane >= d) v += t; }
        if (lane == 63) wsum[w] = v;
        __syncthreads();
        if (w == 0 && lane < 16) {
            int s = wsum[lane];
            #pragma unroll
            for (int d = 1; d < 16; d <<= 1) { int t = __shfl_up(s, d); if (lane >= d) s += t; }
            wsum[lane] = s;
        }
        __syncthreads();
        int wpre = (w == 0) ? 0 : wsum[w - 1];
        int total = wsum[15];
        int excl = base + wpre + (v - tsum);
        if (i0 + 0 < NN) offs[i0 + 0] = excl;
        if (i0 + 1 < NN) offs[i0 + 1] = excl + d0;
        if (i0 + 2 < NN) offs[i0 + 2] = excl + d0 + d1;
        if (i0 + 3 < NN) offs[i0 + 3] = excl + d0 + d1 + d2;
        base += total;
        __syncthreads();
    }
    if (tid == 0) offs[NN] = base;
}

__global__ void k_scatter(const void* edges, const int* flag, const int* offs,
                          int* cursor, int* ssrc) {
    int e = blockIdx.x * 256 + threadIdx.x;
    if (e >= NE) return;
    int is64 = *flag;
    int s = edge_at(edges, is64, e);
    int dst = edge_at(edges, is64, NE + e);
    int pos = atomicAdd(&cursor[dst], 1);
    ssrc[offs[dst] + pos] = s;
}

// ---------------------------------------------------------------------------
// x fp32 [NN,128] -> bf16 into A1 cols 128:256 (A1 is [NN,256] bf16)
// ---------------------------------------------------------------------------
__global__ void k_cvt_x(const float* __restrict__ x, unsigned short* __restrict__ A1) {
    int t = blockIdx.x * 256 + threadIdx.x;
    if (t >= NN * 32) return;
    int node = t >> 5, q = t & 31;
    float4 v = *(const float4*)(x + (size_t)node * 128 + q * 4);
    uint32 p0 = f2bf(v.x) | ((uint32)f2bf(v.y) << 16);
    uint32 p1 = f2bf(v.z) | ((uint32)f2bf(v.w) << 16);
    *(uint2*)(A1 + (size_t)node * 256 + 128 + q * 4) = make_uint2(p0, p1);
}

// pack both weight matrices, n-major transposed bf16 [256][256]
__global__ void k_cvt_w(const float* __restrict__ W1l, const float* __restrict__ W1r,
                        const float* __restrict__ W2l, const float* __restrict__ W2r,
                        unsigned short* __restrict__ B1t, unsigned short* __restrict__ B2t) {
    int t = blockIdx.x * 256 + threadIdx.x;
    if (t >= 65536) return;
    int n = t >> 8, k = t & 255;
    float v1 = (k < 128) ? W1l[k * 256 + n] : W1r[(k - 128) * 256 + n];
    B1t[n * 256 + k] = f2bf(v1);
    float v2 = (n < 128) ? W2l[k * 128 + n] : W2r[k * 128 + (n - 128)];
    B2t[n * 256 + k] = f2bf(v2);
}

// ---------------------------------------------------------------------------
// mean-aggregate bf16 rows (A1 cols 128:256) -> bf16 (A1 cols 0:128)
// one wave per node; lane holds channels 2l, 2l+1 (one uint = full 256B row)
// ---------------------------------------------------------------------------
__global__ void k_agg(unsigned short* __restrict__ A1, const int* __restrict__ offs,
                      const int* __restrict__ ssrc) {
    int node = blockIdx.x * 4 + (threadIdx.x >> 6);
    int lane = threadIdx.x & 63;
    if (node >= NN) return;
    int s0 = offs[node], s1 = offs[node + 1];
    float a0 = 0.f, a1 = 0.f;
    for (int e = s0; e < s1; ++e) {
        int s = ssrc[e];
        uint32 v = *(const uint32*)(A1 + (size_t)s * 256 + 128 + lane * 2);
        a0 += __builtin_bit_cast(float, v << 16);
        a1 += __builtin_bit_cast(float, v & 0xFFFF0000u);
    }
    float inv = 1.0f / fmaxf((float)(s1 - s0), 1.0f);
    uint32 p = f2bf(a0 * inv) | ((uint32)f2bf(a1 * inv) << 16);
    *(uint32*)(A1 + (size_t)node * 256 + lane * 2) = p;
}

// ---------------------------------------------------------------------------
// bf16 MFMA GEMM: [NN,256] @ [256,256] -> [NN,256] bf16
// 128x128 tile, 4 waves (2x2), 4x4 frags of 16x16x32, BK=32, padded LDS
// RELU: C = relu(acc + bias)  else C = acc
// ---------------------------------------------------------------------------
template <bool RELU>
__global__ __launch_bounds__(256)
void k_gemm_bf(const unsigned short* __restrict__ A, const unsigned short* __restrict__ Bt,
               const float* __restrict__ bias, unsigned short* __restrict__ C) {
    constexpr int LDK = 40;  // 32 + 8 bf16 pad (80B row stride)
    __shared__ unsigned short Asm[128][LDK];
    __shared__ unsigned short Bsm[128][LDK];
    int t = threadIdx.x;
    int lane = t & 63, w = t >> 6;
    int m0 = blockIdx.x * 128, n0 = blockIdx.y * 128;
    int wr = (w >> 1) * 64, wc = (w & 1) * 64;
    int fr = lane & 15, fk = (lane >> 4) * 8;

    f32x4 acc[4][4] = {};
    int ml = t >> 2, sub = t & 3;

    for (int k0 = 0; k0 < 256; k0 += 32) {
        #pragma unroll
        for (int h = 0; h < 2; ++h) {
            int row = ml + h * 64;
            int gm = m0 + row;
            short8 v = {};
            if (gm < NN) v = *(const short8*)(A + (size_t)gm * 256 + k0 + sub * 8);
            *(short8*)&Asm[row][sub * 8] = v;
        }
        #pragma unroll
        for (int h = 0; h < 2; ++h) {
            int row = ml + h * 64;
            short8 v = *(const short8*)(Bt + (size_t)(n0 + row) * 256 + k0 + sub * 8);
            *(short8*)&Bsm[row][sub * 8] = v;
        }
        __syncthreads();
        short8 af[4], bfr[4];
        #pragma unroll
        for (int i = 0; i < 4; ++i) af[i] = *(const short8*)&Asm[wr + i * 16 + fr][fk];
        #pragma unroll
        for (int j = 0; j < 4; ++j) bfr[j] = *(const short8*)&Bsm[wc + j * 16 + fr][fk];
        #pragma unroll
        for (int i = 0; i < 4; ++i)
            #pragma unroll
            for (int j = 0; j < 4; ++j)
                acc[i][j] = __builtin_amdgcn_mfma_f32_16x16x32_bf16(af[i], bfr[j], acc[i][j], 0, 0, 0);
        __syncthreads();
    }

    int r0 = (lane >> 4) * 4;
    #pragma unroll
    for (int i = 0; i < 4; ++i) {
        #pragma unroll
        for (int j = 0; j < 4; ++j) {
            int gn = n0 + wc + j * 16 + fr;
            float bb = RELU ? bias[gn] : 0.f;
            #pragma unroll
            for (int rr = 0; rr < 4; ++rr) {
                int gm = m0 + wr + i * 16 + r0 + rr;
                if (gm >= NN) continue;
                float v = acc[i][j][rr];
                if (RELU) v = fmaxf(v + bb, 0.f);
                C[(size_t)gm * 256 + gn] = f2bf(v);
            }
        }
    }
}

// ---------------------------------------------------------------------------
// out = log_softmax( mean_agg(p) + r + b2 ); p = P cols 0:128, r = cols 128:256
// ---------------------------------------------------------------------------
__global__ void k_final(const unsigned short* __restrict__ P, const int* __restrict__ offs,
                        const int* __restrict__ ssrc, const float* __restrict__ b2,
                        float* __restrict__ out) {
    int node = blockIdx.x * 4 + (threadIdx.x >> 6);
    int lane = threadIdx.x & 63;
    if (node >= NN) return;
    int s0 = offs[node], s1 = offs[node + 1];
    float a0 = 0.f, a1 = 0.f;
    for (int e = s0; e < s1; ++e) {
        int s = ssrc[e];
        uint32 v = *(const uint32*)(P + (size_t)s * 256 + lane * 2);
        a0 += __builtin_bit_cast(float, v << 16);
        a1 += __builtin_bit_cast(float, v & 0xFFFF0000u);
    }
    float inv = 1.0f / fmaxf((float)(s1 - s0), 1.0f);
    uint32 rv = *(const uint32*)(P + (size_t)node * 256 + 128 + lane * 2);
    float2 bb = *(const float2*)(b2 + lane * 2);
    float v0 = a0 * inv + __builtin_bit_cast(float, rv << 16) + bb.x;
    float v1 = a1 * inv + __builtin_bit_cast(float, rv & 0xFFFF0000u) + bb.y;

    float mx = fmaxf(v0, v1);
    #pragma unroll
    for (int d = 1; d < 64; d <<= 1) mx = fmaxf(mx, __shfl_xor(mx, d));
    float s = __expf(v0 - mx) + __expf(v1 - mx);
    #pragma unroll
    for (int d = 1; d < 64; d <<= 1) s += __shfl_xor(s, d);
    float ls = logf(s);
    *(float2*)(out + (size_t)node * 128 + lane * 2) = make_float2(v0 - mx - ls, v1 - mx - ls);
}

// ---------------------------------------------------------------------------
extern "C" void kernel_launch(void* const* d_in, const int* in_sizes, int n_in,
                              void* d_out, int out_size, void* d_ws, size_t ws_size,
                              hipStream_t stream) {
    const float* x   = (const float*)d_in[0];
    const void*  edg = d_in[1];
    const float* W1l = (const float*)d_in[2];
    const float* W1r = (const float*)d_in[3];
    const float* b1  = (const float*)d_in[4];
    const float* W2l = (const float*)d_in[5];
    const float* W2r = (const float*)d_in[6];
    const float* b2  = (const float*)d_in[7];
    float* out = (float*)d_out;

    char* ws = (char*)d_ws;
    size_t off = 0;
    auto alloc = [&](size_t bytes) {
        size_t cur = off;
        off = (off + bytes + 255) & ~(size_t)255;
        return cur;
    };
    int* flag   = (int*)(ws + alloc(4));
    int* deg    = (int*)(ws + alloc((size_t)NN * 4));
    int* offs   = (int*)(ws + alloc((size_t)(NN + 1) * 4));
    int* cursor = (int*)(ws + alloc((size_t)NN * 4));
    int* ssrc   = (int*)(ws + alloc((size_t)NE * 4));
    unsigned short* A1  = (unsigned short*)(ws + alloc((size_t)NN * 256 * 2)); // [agg|x] bf16
    unsigned short* Hb  = (unsigned short*)(ws + alloc((size_t)NN * 256 * 2)); // h bf16
    unsigned short* Pb  = (unsigned short*)(ws + alloc((size_t)NN * 256 * 2)); // [p|r] bf16
    unsigned short* B1t = (unsigned short*)(ws + alloc((size_t)65536 * 2));
    unsigned short* B2t = (unsigned short*)(ws + alloc((size_t)65536 * 2));

    int nb_n = (NN + 255) / 256;
    int nb_e = (NE + 255) / 256;
    int nb_w = (NN + 3) / 4;
    int mblocks = (NN + 127) / 128;  // 391

    k_init<<<nb_n, 256, 0, stream>>>(flag, deg, cursor, edg);
    k_hist<<<nb_e, 256, 0, stream>>>(edg, flag, deg);
    k_scan<<<1, 1024, 0, stream>>>(deg, offs);
    k_scatter<<<nb_e, 256, 0, stream>>>(edg, flag, offs, cursor, ssrc);
    k_cvt_x<<<(NN * 32 + 255) / 256, 256, 0, stream>>>(x, A1);
    k_cvt_w<<<256, 256, 0, stream>>>(W1l, W1r, W2l, W2r, B1t, B2t);
    // agg1 -> A1 cols 0:128
    k_agg<<<nb_w, 256, 0, stream>>>(A1, offs, ssrc);
    // h = relu(A1 @ B1 + b1) -> Hb
    k_gemm_bf<true><<<dim3(mblocks, 2), 256, 0, stream>>>(A1, B1t, b1, Hb);
    // [p|r] = Hb @ B2 -> Pb
    k_gemm_bf<false><<<dim3(mblocks, 2), 256, 0, stream>>>(Hb, B2t, nullptr, Pb);
    // out = log_softmax(mean_agg(p) + r + b2)
    k_final<<<nb_w, 256, 0, stream>>>(Pb, offs, ssrc, b2, out);
}

// Round 3
// 229.837 us; speedup vs baseline: 2.0923x; 1.3965x over previous
//
#include <hip/hip_runtime.h>
#include <math.h>

#define NN 50000
#define NE 800000

typedef __attribute__((ext_vector_type(8))) short short8;
typedef __attribute__((ext_vector_type(4))) float f32x4;
typedef unsigned int uint32;

__device__ inline unsigned short f2bf(float f) {
    unsigned u = __builtin_bit_cast(unsigned, f);
    u += 0x7FFF + ((u >> 16) & 1);   // RNE
    return (unsigned short)(u >> 16);
}

// ---------------------------------------------------------------------------
// init: zero deg/cursor; detect edge dtype (int64 vs int32) into flag
// ---------------------------------------------------------------------------
__global__ void k_init(int* flag, int* deg, int* cursor, const void* edges) {
    int i = blockIdx.x * 256 + threadIdx.x;
    if (i < NN) { deg[i] = 0; cursor[i] = 0; }
    if (blockIdx.x == 0 && threadIdx.x < 64) {
        const long long* q = (const long long*)edges;
        long long v = q[threadIdx.x];
        int ok = (v >= 0 && v < NN) ? 1 : 0;
        unsigned long long m = __ballot(ok);
        if (threadIdx.x == 0) *flag = (m == ~0ull) ? 1 : 0;
    }
}

__device__ inline int edge_at(const void* edges, int is64, int i) {
    return is64 ? (int)((const long long*)edges)[i] : ((const int*)edges)[i];
}

__global__ void k_hist(const void* edges, const int* flag, int* deg) {
    int e = blockIdx.x * 256 + threadIdx.x;
    if (e >= NE) return;
    int is64 = *flag;
    int dst = edge_at(edges, is64, NE + e);
    atomicAdd(&deg[dst], 1);
}

// exclusive scan of deg -> offs (single block, 1024 thr, 4 elems/thread)
__global__ void k_scan(const int* deg, int* offs) {
    __shared__ int wsum[16];
    int tid = threadIdx.x, lane = tid & 63, w = tid >> 6;
    int base = 0;
    for (int start = 0; start < NN; start += 4096) {
        int i0 = start + tid * 4;
        int d0 = 0, d1 = 0, d2 = 0, d3 = 0;
        if (i0 + 3 < NN) {
            int4 q = *(const int4*)(deg + i0);
            d0 = q.x; d1 = q.y; d2 = q.z; d3 = q.w;
        } else {
            if (i0 + 0 < NN) d0 = deg[i0 + 0];
            if (i0 + 1 < NN) d1 = deg[i0 + 1];
            if (i0 + 2 < NN) d2 = deg[i0 + 2];
            if (i0 + 3 < NN) d3 = deg[i0 + 3];
        }
        int tsum = d0 + d1 + d2 + d3;
        int v = tsum;
        #pragma unroll
        for (int d = 1; d < 64; d <<= 1) { int t = __shfl_up(v, d); if (lane >= d) v += t; }
        if (lane == 63) wsum[w] = v;
        __syncthreads();
        if (w == 0 && lane < 16) {
            int s = wsum[lane];
            #pragma unroll
            for (int d = 1; d < 16; d <<= 1) { int t = __shfl_up(s, d); if (lane >= d) s += t; }
            wsum[lane] = s;
        }
        __syncthreads();
        int wpre = (w == 0) ? 0 : wsum[w - 1];
        int total = wsum[15];
        int excl = base + wpre + (v - tsum);
        if (i0 + 0 < NN) offs[i0 + 0] = excl;
        if (i0 + 1 < NN) offs[i0 + 1] = excl + d0;
        if (i0 + 2 < NN) offs[i0 + 2] = excl + d0 + d1;
        if (i0 + 3 < NN) offs[i0 + 3] = excl + d0 + d1 + d2;
        base += total;
        __syncthreads();
    }
    if (tid == 0) offs[NN] = base;
}

__global__ void k_scatter(const void* edges, const int* flag, const int* offs,
                          int* cursor, int* ssrc) {
    int e = blockIdx.x * 256 + threadIdx.x;
    if (e >= NE) return;
    int is64 = *flag;
    int s = edge_at(edges, is64, e);
    int dst = edge_at(edges, is64, NE + e);
    int pos = atomicAdd(&cursor[dst], 1);
    ssrc[offs[dst] + pos] = s;
}

// ---------------------------------------------------------------------------
// x fp32 [NN,128] -> bf16 into A1 cols 128:256 (A1 is [NN,256] bf16)
// ---------------------------------------------------------------------------
__global__ void k_cvt_x(const float* __restrict__ x, unsigned short* __restrict__ A1) {
    int t = blockIdx.x * 256 + threadIdx.x;
    if (t >= NN * 32) return;
    int node = t >> 5, q = t & 31;
    float4 v = *(const float4*)(x + (size_t)node * 128 + q * 4);
    uint32 p0 = f2bf(v.x) | ((uint32)f2bf(v.y) << 16);
    uint32 p1 = f2bf(v.z) | ((uint32)f2bf(v.w) << 16);
    *(uint2*)(A1 + (size_t)node * 256 + 128 + q * 4) = make_uint2(p0, p1);
}

// pack both weight matrices, n-major transposed bf16 [256][256]
__global__ void k_cvt_w(const float* __restrict__ W1l, const float* __restrict__ W1r,
                        const float* __restrict__ W2l, const float* __restrict__ W2r,
                        unsigned short* __restrict__ B1t, unsigned short* __restrict__ B2t) {
    int t = blockIdx.x * 256 + threadIdx.x;
    if (t >= 65536) return;
    int n = t >> 8, k = t & 255;
    float v1 = (k < 128) ? W1l[k * 256 + n] : W1r[(k - 128) * 256 + n];
    B1t[n * 256 + k] = f2bf(v1);
    float v2 = (n < 128) ? W2l[k * 128 + n] : W2r[k * 128 + (n - 128)];
    B2t[n * 256 + k] = f2bf(v2);
}

// ---------------------------------------------------------------------------
// burst-gather mean aggregation helper: sums rows (uint32 = 2 bf16 per lane)
// of `tab` (row stride 256 bf16, column offset coff) over ssrc[s0:s1].
// Vector-loads up to 64 edge indices at once, issues gathers 8-deep.
// ---------------------------------------------------------------------------
__device__ inline void burst_gather(const unsigned short* __restrict__ tab, int coff,
                                    const int* __restrict__ ssrc, int s0, int s1,
                                    int lane, float& a0, float& a1) {
    const unsigned short* bp = tab + coff + lane * 2;
    int e = s0;
    while (e < s1) {
        int cnt = s1 - e; if (cnt > 64) cnt = 64;
        int myidx = (lane < cnt) ? ssrc[e + lane] : 0;
        int full = cnt & ~7;
        for (int b = 0; b < full; b += 8) {
            uint32 v[8];
            #pragma unroll
            for (int u = 0; u < 8; ++u) {
                int s = __shfl(myidx, b + u);
                v[u] = *(const uint32*)(bp + (size_t)s * 256);
            }
            #pragma unroll
            for (int u = 0; u < 8; ++u) {
                a0 += __builtin_bit_cast(float, v[u] << 16);
                a1 += __builtin_bit_cast(float, v[u] & 0xFFFF0000u);
            }
        }
        for (int b = full; b < cnt; ++b) {
            int s = __shfl(myidx, b);
            uint32 v = *(const uint32*)(bp + (size_t)s * 256);
            a0 += __builtin_bit_cast(float, v << 16);
            a1 += __builtin_bit_cast(float, v & 0xFFFF0000u);
        }
        e += cnt;
    }
}

// ---------------------------------------------------------------------------
// mean-aggregate bf16 rows (A1 cols 128:256) -> bf16 (A1 cols 0:128)
// one wave per node; lane holds channels 2l, 2l+1
// ---------------------------------------------------------------------------
__global__ void k_agg(unsigned short* __restrict__ A1, const int* __restrict__ offs,
                      const int* __restrict__ ssrc) {
    int node = blockIdx.x * 4 + (threadIdx.x >> 6);
    int lane = threadIdx.x & 63;
    if (node >= NN) return;
    int s0 = offs[node], s1 = offs[node + 1];
    float a0 = 0.f, a1 = 0.f;
    burst_gather(A1, 128, ssrc, s0, s1, lane, a0, a1);
    float inv = 1.0f / fmaxf((float)(s1 - s0), 1.0f);
    uint32 p = f2bf(a0 * inv) | ((uint32)f2bf(a1 * inv) << 16);
    *(uint32*)(A1 + (size_t)node * 256 + lane * 2) = p;
}

// ---------------------------------------------------------------------------
// bf16 MFMA GEMM: [NN,256] @ [256,256] -> [NN,256] bf16
// 128x128 tile, 4 waves (2x2), 4x4 frags of 16x16x32, BK=32, padded LDS
// ---------------------------------------------------------------------------
template <bool RELU>
__global__ __launch_bounds__(256)
void k_gemm_bf(const unsigned short* __restrict__ A, const unsigned short* __restrict__ Bt,
               const float* __restrict__ bias, unsigned short* __restrict__ C) {
    constexpr int LDK = 40;  // 32 + 8 bf16 pad
    __shared__ unsigned short Asm[128][LDK];
    __shared__ unsigned short Bsm[128][LDK];
    int t = threadIdx.x;
    int lane = t & 63, w = t >> 6;
    int m0 = blockIdx.x * 128, n0 = blockIdx.y * 128;
    int wr = (w >> 1) * 64, wc = (w & 1) * 64;
    int fr = lane & 15, fk = (lane >> 4) * 8;

    f32x4 acc[4][4] = {};
    int ml = t >> 2, sub = t & 3;

    for (int k0 = 0; k0 < 256; k0 += 32) {
        #pragma unroll
        for (int h = 0; h < 2; ++h) {
            int row = ml + h * 64;
            int gm = m0 + row;
            short8 v = {};
            if (gm < NN) v = *(const short8*)(A + (size_t)gm * 256 + k0 + sub * 8);
            *(short8*)&Asm[row][sub * 8] = v;
        }
        #pragma unroll
        for (int h = 0; h < 2; ++h) {
            int row = ml + h * 64;
            short8 v = *(const short8*)(Bt + (size_t)(n0 + row) * 256 + k0 + sub * 8);
            *(short8*)&Bsm[row][sub * 8] = v;
        }
        __syncthreads();
        short8 af[4], bfr[4];
        #pragma unroll
        for (int i = 0; i < 4; ++i) af[i] = *(const short8*)&Asm[wr + i * 16 + fr][fk];
        #pragma unroll
        for (int j = 0; j < 4; ++j) bfr[j] = *(const short8*)&Bsm[wc + j * 16 + fr][fk];
        #pragma unroll
        for (int i = 0; i < 4; ++i)
            #pragma unroll
            for (int j = 0; j < 4; ++j)
                acc[i][j] = __builtin_amdgcn_mfma_f32_16x16x32_bf16(af[i], bfr[j], acc[i][j], 0, 0, 0);
        __syncthreads();
    }

    int r0 = (lane >> 4) * 4;
    #pragma unroll
    for (int i = 0; i < 4; ++i) {
        #pragma unroll
        for (int j = 0; j < 4; ++j) {
            int gn = n0 + wc + j * 16 + fr;
            float bb = RELU ? bias[gn] : 0.f;
            #pragma unroll
            for (int rr = 0; rr < 4; ++rr) {
                int gm = m0 + wr + i * 16 + r0 + rr;
                if (gm >= NN) continue;
                float v = acc[i][j][rr];
                if (RELU) v = fmaxf(v + bb, 0.f);
                C[(size_t)gm * 256 + gn] = f2bf(v);
            }
        }
    }
}

// ---------------------------------------------------------------------------
// out = log_softmax( mean_agg(p) + r + b2 ); p = P cols 0:128, r = cols 128:256
// ---------------------------------------------------------------------------
__global__ void k_final(const unsigned short* __restrict__ P, const int* __restrict__ offs,
                        const int* __restrict__ ssrc, const float* __restrict__ b2,
                        float* __restrict__ out) {
    int node = blockIdx.x * 4 + (threadIdx.x >> 6);
    int lane = threadIdx.x & 63;
    if (node >= NN) return;
    int s0 = offs[node], s1 = offs[node + 1];
    float a0 = 0.f, a1 = 0.f;
    burst_gather(P, 0, ssrc, s0, s1, lane, a0, a1);
    float inv = 1.0f / fmaxf((float)(s1 - s0), 1.0f);
    uint32 rv = *(const uint32*)(P + (size_t)node * 256 + 128 + lane * 2);
    float2 bb = *(const float2*)(b2 + lane * 2);
    float v0 = a0 * inv + __builtin_bit_cast(float, rv << 16) + bb.x;
    float v1 = a1 * inv + __builtin_bit_cast(float, rv & 0xFFFF0000u) + bb.y;

    float mx = fmaxf(v0, v1);
    #pragma unroll
    for (int d = 1; d < 64; d <<= 1) mx = fmaxf(mx, __shfl_xor(mx, d));
    float s = __expf(v0 - mx) + __expf(v1 - mx);
    #pragma unroll
    for (int d = 1; d < 64; d <<= 1) s += __shfl_xor(s, d);
    float ls = logf(s);
    *(float2*)(out + (size_t)node * 128 + lane * 2) = make_float2(v0 - mx - ls, v1 - mx - ls);
}

// ---------------------------------------------------------------------------
extern "C" void kernel_launch(void* const* d_in, const int* in_sizes, int n_in,
                              void* d_out, int out_size, void* d_ws, size_t ws_size,
                              hipStream_t stream) {
    const float* x   = (const float*)d_in[0];
    const void*  edg = d_in[1];
    const float* W1l = (const float*)d_in[2];
    const float* W1r = (const float*)d_in[3];
    const float* b1  = (const float*)d_in[4];
    const float* W2l = (const float*)d_in[5];
    const float* W2r = (const float*)d_in[6];
    const float* b2  = (const float*)d_in[7];
    float* out = (float*)d_out;

    char* ws = (char*)d_ws;
    size_t off = 0;
    auto alloc = [&](size_t bytes) {
        size_t cur = off;
        off = (off + bytes + 255) & ~(size_t)255;
        return cur;
    };
    int* flag   = (int*)(ws + alloc(4));
    int* deg    = (int*)(ws + alloc((size_t)NN * 4));
    int* offs   = (int*)(ws + alloc((size_t)(NN + 1) * 4));
    int* cursor = (int*)(ws + alloc((size_t)NN * 4));
    int* ssrc   = (int*)(ws + alloc((size_t)NE * 4));
    unsigned short* A1  = (unsigned short*)(ws + alloc((size_t)NN * 256 * 2)); // [agg|x] bf16
    unsigned short* Hb  = (unsigned short*)(ws + alloc((size_t)NN * 256 * 2)); // h bf16
    unsigned short* Pb  = (unsigned short*)(ws + alloc((size_t)NN * 256 * 2)); // [p|r] bf16
    unsigned short* B1t = (unsigned short*)(ws + alloc((size_t)65536 * 2));
    unsigned short* B2t = (unsigned short*)(ws + alloc((size_t)65536 * 2));

    int nb_n = (NN + 255) / 256;
    int nb_e = (NE + 255) / 256;
    int nb_w = (NN + 3) / 4;
    int mblocks = (NN + 127) / 128;  // 391

    k_init<<<nb_n, 256, 0, stream>>>(flag, deg, cursor, edg);
    k_hist<<<nb_e, 256, 0, stream>>>(edg, flag, deg);
    k_scan<<<1, 1024, 0, stream>>>(deg, offs);
    k_scatter<<<nb_e, 256, 0, stream>>>(edg, flag, offs, cursor, ssrc);
    k_cvt_x<<<(NN * 32 + 255) / 256, 256, 0, stream>>>(x, A1);
    k_cvt_w<<<256, 256, 0, stream>>>(W1l, W1r, W2l, W2r, B1t, B2t);
    // agg1 -> A1 cols 0:128
    k_agg<<<nb_w, 256, 0, stream>>>(A1, offs, ssrc);
    // h = relu(A1 @ B1 + b1) -> Hb
    k_gemm_bf<true><<<dim3(mblocks, 2), 256, 0, stream>>>(A1, B1t, b1, Hb);
    // [p|r] = Hb @ B2 -> Pb
    k_gemm_bf<false><<<dim3(mblocks, 2), 256, 0, stream>>>(Hb, B2t, nullptr, Pb);
    // out = log_softmax(mean_agg(p) + r + b2)
    k_final<<<nb_w, 256, 0, stream>>>(Pb, offs, ssrc, b2, out);
}

// Round 4
// 183.085 us; speedup vs baseline: 2.6266x; 1.2554x over previous
//
#include <hip/hip_runtime.h>
#include <math.h>

#define NN 50000
#define NE 800000
#define BINW 512
#define NB ((NN + BINW - 1) / BINW)   // 98 buckets
#define CAP 12288                     // per-bucket capacity (mean 8192, sd ~90)
#define CHUNK 4096

typedef __attribute__((ext_vector_type(8))) short short8;
typedef __attribute__((ext_vector_type(4))) float f32x4;
typedef unsigned int uint32;
typedef unsigned short ushort16;

__device__ inline unsigned short f2bf(float f) {
    unsigned u = __builtin_bit_cast(unsigned, f);
    u += 0x7FFF + ((u >> 16) & 1);   // RNE
    return (unsigned short)(u >> 16);
}

__device__ inline int edge_at(const void* edges, int is64, int i) {
    return is64 ? (int)((const long long*)edges)[i] : ((const int*)edges)[i];
}

// ---------------------------------------------------------------------------
// init: zero bucket counters; detect edge dtype (int64 vs int32) into flag
// ---------------------------------------------------------------------------
__global__ void k_init(int* flag, int* bcnt, const void* edges) {
    int i = blockIdx.x * 256 + threadIdx.x;
    if (i < NB) bcnt[i] = 0;
    if (blockIdx.x == 0 && threadIdx.x < 64) {
        const long long* q = (const long long*)edges;
        long long v = q[threadIdx.x];
        int ok = (v >= 0 && v < NN) ? 1 : 0;
        unsigned long long m = __ballot(ok);
        if (threadIdx.x == 0) *flag = (m == ~0ull) ? 1 : 0;
    }
}

// ---------------------------------------------------------------------------
// k_bin: coarse counting-sort of edges into NB buckets by dst>>9.
// All global writes are contiguous runs (LDS-sorted first).
// ---------------------------------------------------------------------------
__global__ __launch_bounds__(256) void k_bin(const void* __restrict__ edges,
                                             const int* __restrict__ flag,
                                             uint32* __restrict__ gbuf,
                                             int* __restrict__ bcnt) {
    __shared__ int hist[NB], excl[NB + 1], cur[NB], gpos[NB];
    __shared__ uint32 sorted[CHUNK];
    int t = threadIdx.x;
    int base = blockIdx.x * CHUNK;
    int n = NE - base; if (n > CHUNK) n = CHUNK;
    int is64 = *flag;
    for (int i = t; i < NB; i += 256) hist[i] = 0;
    __syncthreads();
    // phase 1: bucket histogram
    for (int i = t; i < n; i += 256) {
        int dst = edge_at(edges, is64, NE + base + i);
        atomicAdd(&hist[dst >> 9], 1);
    }
    __syncthreads();
    // phase 2: serial scan (98 elems) + global reserve
    if (t == 0) {
        int s = 0;
        for (int b = 0; b < NB; ++b) { excl[b] = s; s += hist[b]; }
        excl[NB] = s;
    }
    __syncthreads();
    if (t < NB) {
        gpos[t] = atomicAdd(&bcnt[t], hist[t]);
        cur[t] = excl[t];
    }
    __syncthreads();
    // phase 3: local sort into LDS (re-read edges, L2-hot)
    for (int i = t; i < n; i += 256) {
        int src = edge_at(edges, is64, base + i);
        int dst = edge_at(edges, is64, NE + base + i);
        int b = dst >> 9;
        int lp = atomicAdd(&cur[b], 1);
        sorted[lp] = ((uint32)(dst & (BINW - 1)) << 16) | (uint32)src;
    }
    __syncthreads();
    // phase 4: coalesced global write (runs of same bucket are contiguous)
    for (int i = t; i < n; i += 256) {
        int lo = 0, hi = NB - 1;   // last b with excl[b] <= i
        while (lo < hi) { int mid = (lo + hi + 1) >> 1; if (excl[mid] <= i) lo = mid; else hi = mid - 1; }
        int gp = gpos[lo] + (i - excl[lo]);
        if (gp < CAP) gbuf[(size_t)lo * CAP + gp] = sorted[i];
    }
}

// tiny scan of bucket counts -> bucket bases; offs[NN] = NE
__global__ void k_bbase(const int* __restrict__ bcnt, int* __restrict__ bbase,
                        int* __restrict__ offs) {
    if (threadIdx.x == 0) {
        int s = 0;
        for (int b = 0; b < NB; ++b) { bbase[b] = s; s += bcnt[b]; }
        offs[NN] = s;
    }
}

// ---------------------------------------------------------------------------
// k_sort: one block per bucket. Counting-sort by local node, emit offs[] and
// the dst-sorted src list (uint16), all writes coalesced.
// ---------------------------------------------------------------------------
__global__ __launch_bounds__(256) void k_sort(const uint32* __restrict__ gbuf,
                                              const int* __restrict__ bcnt,
                                              const int* __restrict__ bbase,
                                              int* __restrict__ offs,
                                              unsigned short* __restrict__ ssrc) {
    __shared__ int hist[BINW], cur[BINW], wsum[4];
    __shared__ int sorted[CAP];
    int b = blockIdx.x, t = threadIdx.x;
    int cnt = bcnt[b]; if (cnt > CAP) cnt = CAP;
    int nbase = b * BINW;
    int ncnt = NN - nbase; if (ncnt > BINW) ncnt = BINW;
    for (int i = t; i < BINW; i += 256) hist[i] = 0;
    __syncthreads();
    for (int i = t; i < cnt; i += 256)
        atomicAdd(&hist[gbuf[(size_t)b * CAP + i] >> 16], 1);
    __syncthreads();
    // exclusive scan of 512 (2 elems/thread, shfl + 4-wave combine)
    int lane = t & 63, w = t >> 6;
    int d0 = hist[2 * t], d1 = hist[2 * t + 1];
    int v = d0 + d1;
    #pragma unroll
    for (int d = 1; d < 64; d <<= 1) { int x = __shfl_up(v, d); if (lane >= d) v += x; }
    if (lane == 63) wsum[w] = v;
    __syncthreads();
    if (t == 0) { int s = 0; for (int i = 0; i < 4; ++i) { int x = wsum[i]; wsum[i] = s; s += x; } }
    __syncthreads();
    int e0 = wsum[w] + (v - d0 - d1);   // exclusive prefix of element 2t
    int e1 = e0 + d0;
    if (2 * t < ncnt)     offs[nbase + 2 * t]     = bbase[b] + e0;
    if (2 * t + 1 < ncnt) offs[nbase + 2 * t + 1] = bbase[b] + e1;
    cur[2 * t] = e0; cur[2 * t + 1] = e1;
    __syncthreads();
    // counting-sort scatter in LDS
    for (int i = t; i < cnt; i += 256) {
        uint32 p = gbuf[(size_t)b * CAP + i];
        int lp = atomicAdd(&cur[p >> 16], 1);
        sorted[lp] = (int)(p & 0xFFFFu);
    }
    __syncthreads();
    // coalesced output
    for (int i = t; i < cnt; i += 256)
        ssrc[bbase[b] + i] = (unsigned short)sorted[i];
}

// ---------------------------------------------------------------------------
// x fp32 [NN,128] -> bf16 into A1 cols 128:256 (A1 is [NN,256] bf16)
// ---------------------------------------------------------------------------
__global__ void k_cvt_x(const float* __restrict__ x, unsigned short* __restrict__ A1) {
    int t = blockIdx.x * 256 + threadIdx.x;
    if (t >= NN * 32) return;
    int node = t >> 5, q = t & 31;
    float4 v = *(const float4*)(x + (size_t)node * 128 + q * 4);
    uint32 p0 = f2bf(v.x) | ((uint32)f2bf(v.y) << 16);
    uint32 p1 = f2bf(v.z) | ((uint32)f2bf(v.w) << 16);
    *(uint2*)(A1 + (size_t)node * 256 + 128 + q * 4) = make_uint2(p0, p1);
}

// pack both weight matrices, n-major transposed bf16 [256][256]
__global__ void k_cvt_w(const float* __restrict__ W1l, const float* __restrict__ W1r,
                        const float* __restrict__ W2l, const float* __restrict__ W2r,
                        unsigned short* __restrict__ B1t, unsigned short* __restrict__ B2t) {
    int t = blockIdx.x * 256 + threadIdx.x;
    if (t >= 65536) return;
    int n = t >> 8, k = t & 255;
    float v1 = (k < 128) ? W1l[k * 256 + n] : W1r[(k - 128) * 256 + n];
    B1t[n * 256 + k] = f2bf(v1);
    float v2 = (n < 128) ? W2l[k * 128 + n] : W2r[k * 128 + (n - 128)];
    B2t[n * 256 + k] = f2bf(v2);
}

// ---------------------------------------------------------------------------
// burst-gather mean aggregation helper (8 gathers in flight)
// ---------------------------------------------------------------------------
__device__ inline void burst_gather(const unsigned short* __restrict__ tab, int coff,
                                    const unsigned short* __restrict__ ssrc, int s0, int s1,
                                    int lane, float& a0, float& a1) {
    const unsigned short* bp = tab + coff + lane * 2;
    int e = s0;
    while (e < s1) {
        int cnt = s1 - e; if (cnt > 64) cnt = 64;
        int myidx = (lane < cnt) ? (int)ssrc[e + lane] : 0;
        int full = cnt & ~7;
        for (int b = 0; b < full; b += 8) {
            uint32 v[8];
            #pragma unroll
            for (int u = 0; u < 8; ++u) {
                int s = __shfl(myidx, b + u);
                v[u] = *(const uint32*)(bp + (size_t)s * 256);
            }
            #pragma unroll
            for (int u = 0; u < 8; ++u) {
                a0 += __builtin_bit_cast(float, v[u] << 16);
                a1 += __builtin_bit_cast(float, v[u] & 0xFFFF0000u);
            }
        }
        for (int b = full; b < cnt; ++b) {
            int s = __shfl(myidx, b);
            uint32 v = *(const uint32*)(bp + (size_t)s * 256);
            a0 += __builtin_bit_cast(float, v << 16);
            a1 += __builtin_bit_cast(float, v & 0xFFFF0000u);
        }
        e += cnt;
    }
}

// ---------------------------------------------------------------------------
// mean-aggregate bf16 rows (A1 cols 128:256) -> bf16 (A1 cols 0:128)
// ---------------------------------------------------------------------------
__global__ void k_agg(unsigned short* __restrict__ A1, const int* __restrict__ offs,
                      const unsigned short* __restrict__ ssrc) {
    int node = blockIdx.x * 4 + (threadIdx.x >> 6);
    int lane = threadIdx.x & 63;
    if (node >= NN) return;
    int s0 = offs[node], s1 = offs[node + 1];
    float a0 = 0.f, a1 = 0.f;
    burst_gather(A1, 128, ssrc, s0, s1, lane, a0, a1);
    float inv = 1.0f / fmaxf((float)(s1 - s0), 1.0f);
    uint32 p = f2bf(a0 * inv) | ((uint32)f2bf(a1 * inv) << 16);
    *(uint32*)(A1 + (size_t)node * 256 + lane * 2) = p;
}

// ---------------------------------------------------------------------------
// bf16 MFMA GEMM: [NN,256] @ [256,256] -> [NN,256] bf16
// 128x128 tile, 4 waves (2x2), 4x4 frags of 16x16x32, BK=32, padded LDS
// ---------------------------------------------------------------------------
template <bool RELU>
__global__ __launch_bounds__(256)
void k_gemm_bf(const unsigned short* __restrict__ A, const unsigned short* __restrict__ Bt,
               const float* __restrict__ bias, unsigned short* __restrict__ C) {
    constexpr int LDK = 40;  // 32 + 8 bf16 pad
    __shared__ unsigned short Asm[128][LDK];
    __shared__ unsigned short Bsm[128][LDK];
    int t = threadIdx.x;
    int lane = t & 63, w = t >> 6;
    int m0 = blockIdx.x * 128, n0 = blockIdx.y * 128;
    int wr = (w >> 1) * 64, wc = (w & 1) * 64;
    int fr = lane & 15, fk = (lane >> 4) * 8;

    f32x4 acc[4][4] = {};
    int ml = t >> 2, sub = t & 3;

    for (int k0 = 0; k0 < 256; k0 += 32) {
        #pragma unroll
        for (int h = 0; h < 2; ++h) {
            int row = ml + h * 64;
            int gm = m0 + row;
            short8 v = {};
            if (gm < NN) v = *(const short8*)(A + (size_t)gm * 256 + k0 + sub * 8);
            *(short8*)&Asm[row][sub * 8] = v;
        }
        #pragma unroll
        for (int h = 0; h < 2; ++h) {
            int row = ml + h * 64;
            short8 v = *(const short8*)(Bt + (size_t)(n0 + row) * 256 + k0 + sub * 8);
            *(short8*)&Bsm[row][sub * 8] = v;
        }
        __syncthreads();
        short8 af[4], bfr[4];
        #pragma unroll
        for (int i = 0; i < 4; ++i) af[i] = *(const short8*)&Asm[wr + i * 16 + fr][fk];
        #pragma unroll
        for (int j = 0; j < 4; ++j) bfr[j] = *(const short8*)&Bsm[wc + j * 16 + fr][fk];
        #pragma unroll
        for (int i = 0; i < 4; ++i)
            #pragma unroll
            for (int j = 0; j < 4; ++j)
                acc[i][j] = __builtin_amdgcn_mfma_f32_16x16x32_bf16(af[i], bfr[j], acc[i][j], 0, 0, 0);
        __syncthreads();
    }

    int r0 = (lane >> 4) * 4;
    #pragma unroll
    for (int i = 0; i < 4; ++i) {
        #pragma unroll
        for (int j = 0; j < 4; ++j) {
            int gn = n0 + wc + j * 16 + fr;
            float bb = RELU ? bias[gn] : 0.f;
            #pragma unroll
            for (int rr = 0; rr < 4; ++rr) {
                int gm = m0 + wr + i * 16 + r0 + rr;
                if (gm >= NN) continue;
                float v = acc[i][j][rr];
                if (RELU) v = fmaxf(v + bb, 0.f);
                C[(size_t)gm * 256 + gn] = f2bf(v);
            }
        }
    }
}

// ---------------------------------------------------------------------------
// out = log_softmax( mean_agg(p) + r + b2 ); p = P cols 0:128, r = cols 128:256
// ---------------------------------------------------------------------------
__global__ void k_final(const unsigned short* __restrict__ P, const int* __restrict__ offs,
                        const unsigned short* __restrict__ ssrc, const float* __restrict__ b2,
                        float* __restrict__ out) {
    int node = blockIdx.x * 4 + (threadIdx.x >> 6);
    int lane = threadIdx.x & 63;
    if (node >= NN) return;
    int s0 = offs[node], s1 = offs[node + 1];
    float a0 = 0.f, a1 = 0.f;
    burst_gather(P, 0, ssrc, s0, s1, lane, a0, a1);
    float inv = 1.0f / fmaxf((float)(s1 - s0), 1.0f);
    uint32 rv = *(const uint32*)(P + (size_t)node * 256 + 128 + lane * 2);
    float2 bb = *(const float2*)(b2 + lane * 2);
    float v0 = a0 * inv + __builtin_bit_cast(float, rv << 16) + bb.x;
    float v1 = a1 * inv + __builtin_bit_cast(float, rv & 0xFFFF0000u) + bb.y;

    float mx = fmaxf(v0, v1);
    #pragma unroll
    for (int d = 1; d < 64; d <<= 1) mx = fmaxf(mx, __shfl_xor(mx, d));
    float s = __expf(v0 - mx) + __expf(v1 - mx);
    #pragma unroll
    for (int d = 1; d < 64; d <<= 1) s += __shfl_xor(s, d);
    float ls = logf(s);
    *(float2*)(out + (size_t)node * 128 + lane * 2) = make_float2(v0 - mx - ls, v1 - mx - ls);
}

// ---------------------------------------------------------------------------
extern "C" void kernel_launch(void* const* d_in, const int* in_sizes, int n_in,
                              void* d_out, int out_size, void* d_ws, size_t ws_size,
                              hipStream_t stream) {
    const float* x   = (const float*)d_in[0];
    const void*  edg = d_in[1];
    const float* W1l = (const float*)d_in[2];
    const float* W1r = (const float*)d_in[3];
    const float* b1  = (const float*)d_in[4];
    const float* W2l = (const float*)d_in[5];
    const float* W2r = (const float*)d_in[6];
    const float* b2  = (const float*)d_in[7];
    float* out = (float*)d_out;

    char* ws = (char*)d_ws;
    size_t off = 0;
    auto alloc = [&](size_t bytes) {
        size_t cur = off;
        off = (off + bytes + 255) & ~(size_t)255;
        return cur;
    };
    int* flag  = (int*)(ws + alloc(4));
    int* bcnt  = (int*)(ws + alloc((size_t)NB * 4));
    int* bbase = (int*)(ws + alloc((size_t)NB * 4));
    int* offs  = (int*)(ws + alloc((size_t)(NN + 1) * 4));
    unsigned short* ssrc = (unsigned short*)(ws + alloc((size_t)NE * 2));
    uint32* gbuf = (uint32*)(ws + alloc((size_t)NB * CAP * 4));              // 4.8MB
    unsigned short* A1  = (unsigned short*)(ws + alloc((size_t)NN * 256 * 2)); // [agg|x] bf16
    unsigned short* Hb  = (unsigned short*)(ws + alloc((size_t)NN * 256 * 2)); // h bf16
    unsigned short* Pb  = (unsigned short*)(ws + alloc((size_t)NN * 256 * 2)); // [p|r] bf16
    unsigned short* B1t = (unsigned short*)(ws + alloc((size_t)65536 * 2));
    unsigned short* B2t = (unsigned short*)(ws + alloc((size_t)65536 * 2));

    int nb_n = (NN + 255) / 256;
    int nb_w = (NN + 3) / 4;
    int mblocks = (NN + 127) / 128;  // 391
    int binblocks = (NE + CHUNK - 1) / CHUNK;  // 196

    k_init<<<nb_n, 256, 0, stream>>>(flag, bcnt, edg);
    k_cvt_x<<<(NN * 32 + 255) / 256, 256, 0, stream>>>(x, A1);
    k_cvt_w<<<256, 256, 0, stream>>>(W1l, W1r, W2l, W2r, B1t, B2t);
    k_bin<<<binblocks, 256, 0, stream>>>(edg, flag, gbuf, bcnt);
    k_bbase<<<1, 64, 0, stream>>>(bcnt, bbase, offs);
    k_sort<<<NB, 256, 0, stream>>>(gbuf, bcnt, bbase, offs, ssrc);
    // agg1 -> A1 cols 0:128
    k_agg<<<nb_w, 256, 0, stream>>>(A1, offs, ssrc);
    // h = relu(A1 @ B1 + b1) -> Hb
    k_gemm_bf<true><<<dim3(mblocks, 2), 256, 0, stream>>>(A1, B1t, b1, Hb);
    // [p|r] = Hb @ B2 -> Pb
    k_gemm_bf<false><<<dim3(mblocks, 2), 256, 0, stream>>>(Hb, B2t, nullptr, Pb);
    // out = log_softmax(mean_agg(p) + r + b2)
    k_final<<<nb_w, 256, 0, stream>>>(Pb, offs, ssrc, b2, out);
}

// Round 5
// 178.759 us; speedup vs baseline: 2.6901x; 1.0242x over previous
//
#include <hip/hip_runtime.h>
#include <math.h>

#define NN 50000
#define NE 800000
#define BINW 512
#define NB ((NN + BINW - 1) / BINW)   // 98 buckets
#define CAP 12288                     // per-bucket capacity (mean 8192, sd ~90)
#define CHUNK 4096

typedef __attribute__((ext_vector_type(8))) short short8;
typedef __attribute__((ext_vector_type(4))) float f32x4;
typedef unsigned int uint32;

__device__ inline unsigned short f2bf(float f) {
    unsigned u = __builtin_bit_cast(unsigned, f);
    u += 0x7FFF + ((u >> 16) & 1);   // RNE
    return (unsigned short)(u >> 16);
}

__device__ inline int edge_at(const void* edges, int is64, int i) {
    return is64 ? (int)((const long long*)edges)[i] : ((const int*)edges)[i];
}

// ---------------------------------------------------------------------------
// init: zero bucket counters; detect edge dtype (int64 vs int32) into flag
// ---------------------------------------------------------------------------
__global__ void k_init(int* flag, int* bcnt, const void* edges) {
    int i = blockIdx.x * 256 + threadIdx.x;
    if (i < NB) bcnt[i] = 0;
    if (blockIdx.x == 0 && threadIdx.x < 64) {
        const long long* q = (const long long*)edges;
        long long v = q[threadIdx.x];
        int ok = (v >= 0 && v < NN) ? 1 : 0;
        unsigned long long m = __ballot(ok);
        if (threadIdx.x == 0) *flag = (m == ~0ull) ? 1 : 0;
    }
}

// ---------------------------------------------------------------------------
// k_bin: coarse counting-sort of edges into NB buckets by dst>>9.
// All global writes are contiguous runs (LDS-sorted first).
// ---------------------------------------------------------------------------
__global__ __launch_bounds__(256) void k_bin(const void* __restrict__ edges,
                                             const int* __restrict__ flag,
                                             uint32* __restrict__ gbuf,
                                             int* __restrict__ bcnt) {
    __shared__ int hist[NB], excl[NB + 1], cur[NB], gpos[NB];
    __shared__ uint32 sorted[CHUNK];
    int t = threadIdx.x;
    int base = blockIdx.x * CHUNK;
    int n = NE - base; if (n > CHUNK) n = CHUNK;
    int is64 = *flag;
    for (int i = t; i < NB; i += 256) hist[i] = 0;
    __syncthreads();
    // phase 1: bucket histogram
    for (int i = t; i < n; i += 256) {
        int dst = edge_at(edges, is64, NE + base + i);
        atomicAdd(&hist[dst >> 9], 1);
    }
    __syncthreads();
    // phase 2: serial scan (98 elems) + global reserve
    if (t == 0) {
        int s = 0;
        for (int b = 0; b < NB; ++b) { excl[b] = s; s += hist[b]; }
        excl[NB] = s;
    }
    __syncthreads();
    if (t < NB) {
        gpos[t] = atomicAdd(&bcnt[t], hist[t]);
        cur[t] = excl[t];
    }
    __syncthreads();
    // phase 3: local sort into LDS (re-read edges, L2-hot)
    for (int i = t; i < n; i += 256) {
        int src = edge_at(edges, is64, base + i);
        int dst = edge_at(edges, is64, NE + base + i);
        int b = dst >> 9;
        int lp = atomicAdd(&cur[b], 1);
        sorted[lp] = ((uint32)(dst & (BINW - 1)) << 16) | (uint32)src;
    }
    __syncthreads();
    // phase 4: coalesced global write (runs of same bucket are contiguous)
    for (int i = t; i < n; i += 256) {
        int lo = 0, hi = NB - 1;   // last b with excl[b] <= i
        while (lo < hi) { int mid = (lo + hi + 1) >> 1; if (excl[mid] <= i) lo = mid; else hi = mid - 1; }
        int gp = gpos[lo] + (i - excl[lo]);
        if (gp < CAP) gbuf[(size_t)lo * CAP + gp] = sorted[i];
    }
}

// tiny scan of bucket counts -> bucket bases; offs[NN] = NE
__global__ void k_bbase(const int* __restrict__ bcnt, int* __restrict__ bbase,
                        int* __restrict__ offs) {
    if (threadIdx.x == 0) {
        int s = 0;
        for (int b = 0; b < NB; ++b) { bbase[b] = s; s += bcnt[b]; }
        offs[NN] = s;
    }
}

// ---------------------------------------------------------------------------
// k_sort: one block per bucket. Counting-sort by local node, emit offs[] and
// the dst-sorted src list (uint16), all writes coalesced.
// ---------------------------------------------------------------------------
__global__ __launch_bounds__(256) void k_sort(const uint32* __restrict__ gbuf,
                                              const int* __restrict__ bcnt,
                                              const int* __restrict__ bbase,
                                              int* __restrict__ offs,
                                              unsigned short* __restrict__ ssrc) {
    __shared__ int hist[BINW], cur[BINW], wsum[4];
    __shared__ int sorted[CAP];
    int b = blockIdx.x, t = threadIdx.x;
    int cnt = bcnt[b]; if (cnt > CAP) cnt = CAP;
    int nbase = b * BINW;
    int ncnt = NN - nbase; if (ncnt > BINW) ncnt = BINW;
    for (int i = t; i < BINW; i += 256) hist[i] = 0;
    __syncthreads();
    for (int i = t; i < cnt; i += 256)
        atomicAdd(&hist[gbuf[(size_t)b * CAP + i] >> 16], 1);
    __syncthreads();
    // exclusive scan of 512 (2 elems/thread, shfl + 4-wave combine)
    int lane = t & 63, w = t >> 6;
    int d0 = hist[2 * t], d1 = hist[2 * t + 1];
    int v = d0 + d1;
    #pragma unroll
    for (int d = 1; d < 64; d <<= 1) { int x = __shfl_up(v, d); if (lane >= d) v += x; }
    if (lane == 63) wsum[w] = v;
    __syncthreads();
    if (t == 0) { int s = 0; for (int i = 0; i < 4; ++i) { int x = wsum[i]; wsum[i] = s; s += x; } }
    __syncthreads();
    int e0 = wsum[w] + (v - d0 - d1);   // exclusive prefix of element 2t
    int e1 = e0 + d0;
    if (2 * t < ncnt)     offs[nbase + 2 * t]     = bbase[b] + e0;
    if (2 * t + 1 < ncnt) offs[nbase + 2 * t + 1] = bbase[b] + e1;
    cur[2 * t] = e0; cur[2 * t + 1] = e1;
    __syncthreads();
    // counting-sort scatter in LDS
    for (int i = t; i < cnt; i += 256) {
        uint32 p = gbuf[(size_t)b * CAP + i];
        int lp = atomicAdd(&cur[p >> 16], 1);
        sorted[lp] = (int)(p & 0xFFFFu);
    }
    __syncthreads();
    // coalesced output
    for (int i = t; i < cnt; i += 256)
        ssrc[bbase[b] + i] = (unsigned short)sorted[i];
}

// ---------------------------------------------------------------------------
// x fp32 [NN,128] -> bf16 into A1 cols 128:256 (A1 is [NN,256] bf16)
// ---------------------------------------------------------------------------
__global__ void k_cvt_x(const float* __restrict__ x, unsigned short* __restrict__ A1) {
    int t = blockIdx.x * 256 + threadIdx.x;
    if (t >= NN * 32) return;
    int node = t >> 5, q = t & 31;
    float4 v = *(const float4*)(x + (size_t)node * 128 + q * 4);
    uint32 p0 = f2bf(v.x) | ((uint32)f2bf(v.y) << 16);
    uint32 p1 = f2bf(v.z) | ((uint32)f2bf(v.w) << 16);
    *(uint2*)(A1 + (size_t)node * 256 + 128 + q * 4) = make_uint2(p0, p1);
}

// pack both weight matrices, n-major transposed bf16 [256][256]
__global__ void k_cvt_w(const float* __restrict__ W1l, const float* __restrict__ W1r,
                        const float* __restrict__ W2l, const float* __restrict__ W2r,
                        unsigned short* __restrict__ B1t, unsigned short* __restrict__ B2t) {
    int t = blockIdx.x * 256 + threadIdx.x;
    if (t >= 65536) return;
    int n = t >> 8, k = t & 255;
    float v1 = (k < 128) ? W1l[k * 256 + n] : W1r[(k - 128) * 256 + n];
    B1t[n * 256 + k] = f2bf(v1);
    float v2 = (n < 128) ? W2l[k * 128 + n] : W2r[k * 128 + (n - 128)];
    B2t[n * 256 + k] = f2bf(v2);
}

// ---------------------------------------------------------------------------
// burst-gather mean aggregation helper (16 gathers in flight)
// ---------------------------------------------------------------------------
__device__ inline void burst_gather(const unsigned short* __restrict__ tab, int coff,
                                    const unsigned short* __restrict__ ssrc, int s0, int s1,
                                    int lane, float& a0, float& a1) {
    const unsigned short* bp = tab + coff + lane * 2;
    int e = s0;
    while (e < s1) {
        int cnt = s1 - e; if (cnt > 64) cnt = 64;
        int myidx = (lane < cnt) ? (int)ssrc[e + lane] : 0;
        int b = 0;
        for (; b + 16 <= cnt; b += 16) {
            uint32 v[16];
            #pragma unroll
            for (int u = 0; u < 16; ++u) {
                int s = __shfl(myidx, b + u);
                v[u] = *(const uint32*)(bp + (size_t)s * 256);
            }
            #pragma unroll
            for (int u = 0; u < 16; ++u) {
                a0 += __builtin_bit_cast(float, v[u] << 16);
                a1 += __builtin_bit_cast(float, v[u] & 0xFFFF0000u);
            }
        }
        for (; b + 8 <= cnt; b += 8) {
            uint32 v[8];
            #pragma unroll
            for (int u = 0; u < 8; ++u) {
                int s = __shfl(myidx, b + u);
                v[u] = *(const uint32*)(bp + (size_t)s * 256);
            }
            #pragma unroll
            for (int u = 0; u < 8; ++u) {
                a0 += __builtin_bit_cast(float, v[u] << 16);
                a1 += __builtin_bit_cast(float, v[u] & 0xFFFF0000u);
            }
        }
        for (; b < cnt; ++b) {
            int s = __shfl(myidx, b);
            uint32 v = *(const uint32*)(bp + (size_t)s * 256);
            a0 += __builtin_bit_cast(float, v << 16);
            a1 += __builtin_bit_cast(float, v & 0xFFFF0000u);
        }
        e += cnt;
    }
}

// ---------------------------------------------------------------------------
// mean-aggregate bf16 rows (A1 cols 128:256) -> bf16 (A1 cols 0:128)
// ---------------------------------------------------------------------------
__global__ void k_agg(unsigned short* __restrict__ A1, const int* __restrict__ offs,
                      const unsigned short* __restrict__ ssrc) {
    int node = blockIdx.x * 4 + (threadIdx.x >> 6);
    int lane = threadIdx.x & 63;
    if (node >= NN) return;
    int s0 = offs[node], s1 = offs[node + 1];
    float a0 = 0.f, a1 = 0.f;
    burst_gather(A1, 128, ssrc, s0, s1, lane, a0, a1);
    float inv = 1.0f / fmaxf((float)(s1 - s0), 1.0f);
    uint32 p = f2bf(a0 * inv) | ((uint32)f2bf(a1 * inv) << 16);
    *(uint32*)(A1 + (size_t)node * 256 + lane * 2) = p;
}

// ---------------------------------------------------------------------------
// bf16 MFMA GEMM: [NN,256] @ [256,256] -> [NN,256] bf16
// 128x128 tile, 4 waves (2x2), 4x4 frags of 16x16x32, BK=32.
// 2-phase pipeline: double-buffered LDS, register-prefetch of K-step k+1
// issued before the ds_read+MFMA of step k; one barrier per K-step.
// ---------------------------------------------------------------------------
template <bool RELU>
__global__ __launch_bounds__(256)
void k_gemm_bf(const unsigned short* __restrict__ A, const unsigned short* __restrict__ Bt,
               const float* __restrict__ bias, unsigned short* __restrict__ C) {
    constexpr int LDK = 40;  // 32 + 8 bf16 pad
    __shared__ unsigned short Asm[2][128][LDK];
    __shared__ unsigned short Bsm[2][128][LDK];
    int t = threadIdx.x;
    int lane = t & 63, w = t >> 6;
    int m0 = blockIdx.x * 128, n0 = blockIdx.y * 128;
    int wr = (w >> 1) * 64, wc = (w & 1) * 64;
    int fr = lane & 15, fk = (lane >> 4) * 8;

    f32x4 acc[4][4] = {};
    int ml = t >> 2, sub = t & 3;
    int gmA0 = m0 + ml, gmA1 = m0 + ml + 64;
    bool okA0 = gmA0 < NN, okA1 = gmA1 < NN;
    const short8* pa0 = (const short8*)(A + (size_t)gmA0 * 256 + sub * 8);
    const short8* pa1 = (const short8*)(A + (size_t)gmA1 * 256 + sub * 8);
    const short8* pb0 = (const short8*)(Bt + (size_t)(n0 + ml) * 256 + sub * 8);
    const short8* pb1 = (const short8*)(Bt + (size_t)(n0 + ml + 64) * 256 + sub * 8);
    const short8 zero = {};

    short8 va0, va1, vb0, vb1;
    // one K-step = 32 cols = 4 short8 along the row
    auto LOAD = [&](int ks) {
        va0 = okA0 ? pa0[ks * 4] : zero;
        va1 = okA1 ? pa1[ks * 4] : zero;
        vb0 = pb0[ks * 4];
        vb1 = pb1[ks * 4];
    };
    auto STORE = [&](int buf) {
        *(short8*)&Asm[buf][ml][sub * 8]      = va0;
        *(short8*)&Asm[buf][ml + 64][sub * 8] = va1;
        *(short8*)&Bsm[buf][ml][sub * 8]      = vb0;
        *(short8*)&Bsm[buf][ml + 64][sub * 8] = vb1;
    };

    LOAD(0);
    STORE(0);
    __syncthreads();
    int cur = 0;
    #pragma unroll
    for (int ks = 0; ks < 8; ++ks) {
        if (ks < 7) LOAD(ks + 1);           // prefetch next K-step (in flight)
        short8 af[4], bfr[4];
        #pragma unroll
        for (int i = 0; i < 4; ++i) af[i] = *(const short8*)&Asm[cur][wr + i * 16 + fr][fk];
        #pragma unroll
        for (int j = 0; j < 4; ++j) bfr[j] = *(const short8*)&Bsm[cur][wc + j * 16 + fr][fk];
        #pragma unroll
        for (int i = 0; i < 4; ++i)
            #pragma unroll
            for (int j = 0; j < 4; ++j)
                acc[i][j] = __builtin_amdgcn_mfma_f32_16x16x32_bf16(af[i], bfr[j], acc[i][j], 0, 0, 0);
        if (ks < 7) {
            STORE(cur ^ 1);                 // waits vmcnt on the prefetch only
            __syncthreads();                // single barrier per K-step
            cur ^= 1;
        }
    }

    int r0 = (lane >> 4) * 4;
    #pragma unroll
    for (int i = 0; i < 4; ++i) {
        #pragma unroll
        for (int j = 0; j < 4; ++j) {
            int gn = n0 + wc + j * 16 + fr;
            float bb = RELU ? bias[gn] : 0.f;
            #pragma unroll
            for (int rr = 0; rr < 4; ++rr) {
                int gm = m0 + wr + i * 16 + r0 + rr;
                if (gm >= NN) continue;
                float v = acc[i][j][rr];
                if (RELU) v = fmaxf(v + bb, 0.f);
                C[(size_t)gm * 256 + gn] = f2bf(v);
            }
        }
    }
}

// ---------------------------------------------------------------------------
// out = log_softmax( mean_agg(p) + r + b2 ); p = P cols 0:128, r = cols 128:256
// ---------------------------------------------------------------------------
__global__ void k_final(const unsigned short* __restrict__ P, const int* __restrict__ offs,
                        const unsigned short* __restrict__ ssrc, const float* __restrict__ b2,
                        float* __restrict__ out) {
    int node = blockIdx.x * 4 + (threadIdx.x >> 6);
    int lane = threadIdx.x & 63;
    if (node >= NN) return;
    int s0 = offs[node], s1 = offs[node + 1];
    float a0 = 0.f, a1 = 0.f;
    burst_gather(P, 0, ssrc, s0, s1, lane, a0, a1);
    float inv = 1.0f / fmaxf((float)(s1 - s0), 1.0f);
    uint32 rv = *(const uint32*)(P + (size_t)node * 256 + 128 + lane * 2);
    float2 bb = *(const float2*)(b2 + lane * 2);
    float v0 = a0 * inv + __builtin_bit_cast(float, rv << 16) + bb.x;
    float v1 = a1 * inv + __builtin_bit_cast(float, rv & 0xFFFF0000u) + bb.y;

    float mx = fmaxf(v0, v1);
    #pragma unroll
    for (int d = 1; d < 64; d <<= 1) mx = fmaxf(mx, __shfl_xor(mx, d));
    float s = __expf(v0 - mx) + __expf(v1 - mx);
    #pragma unroll
    for (int d = 1; d < 64; d <<= 1) s += __shfl_xor(s, d);
    float ls = logf(s);
    *(float2*)(out + (size_t)node * 128 + lane * 2) = make_float2(v0 - mx - ls, v1 - mx - ls);
}

// ---------------------------------------------------------------------------
extern "C" void kernel_launch(void* const* d_in, const int* in_sizes, int n_in,
                              void* d_out, int out_size, void* d_ws, size_t ws_size,
                              hipStream_t stream) {
    const float* x   = (const float*)d_in[0];
    const void*  edg = d_in[1];
    const float* W1l = (const float*)d_in[2];
    const float* W1r = (const float*)d_in[3];
    const float* b1  = (const float*)d_in[4];
    const float* W2l = (const float*)d_in[5];
    const float* W2r = (const float*)d_in[6];
    const float* b2  = (const float*)d_in[7];
    float* out = (float*)d_out;

    char* ws = (char*)d_ws;
    size_t off = 0;
    auto alloc = [&](size_t bytes) {
        size_t cur = off;
        off = (off + bytes + 255) & ~(size_t)255;
        return cur;
    };
    int* flag  = (int*)(ws + alloc(4));
    int* bcnt  = (int*)(ws + alloc((size_t)NB * 4));
    int* bbase = (int*)(ws + alloc((size_t)NB * 4));
    int* offs  = (int*)(ws + alloc((size_t)(NN + 1) * 4));
    unsigned short* ssrc = (unsigned short*)(ws + alloc((size_t)NE * 2));
    uint32* gbuf = (uint32*)(ws + alloc((size_t)NB * CAP * 4));              // 4.8MB
    unsigned short* A1  = (unsigned short*)(ws + alloc((size_t)NN * 256 * 2)); // [agg|x] bf16
    unsigned short* Hb  = (unsigned short*)(ws + alloc((size_t)NN * 256 * 2)); // h bf16
    unsigned short* Pb  = (unsigned short*)(ws + alloc((size_t)NN * 256 * 2)); // [p|r] bf16
    unsigned short* B1t = (unsigned short*)(ws + alloc((size_t)65536 * 2));
    unsigned short* B2t = (unsigned short*)(ws + alloc((size_t)65536 * 2));

    int nb_n = (NN + 255) / 256;
    int nb_w = (NN + 3) / 4;
    int mblocks = (NN + 127) / 128;  // 391
    int binblocks = (NE + CHUNK - 1) / CHUNK;  // 196

    k_init<<<nb_n, 256, 0, stream>>>(flag, bcnt, edg);
    k_cvt_x<<<(NN * 32 + 255) / 256, 256, 0, stream>>>(x, A1);
    k_cvt_w<<<256, 256, 0, stream>>>(W1l, W1r, W2l, W2r, B1t, B2t);
    k_bin<<<binblocks, 256, 0, stream>>>(edg, flag, gbuf, bcnt);
    k_bbase<<<1, 64, 0, stream>>>(bcnt, bbase, offs);
    k_sort<<<NB, 256, 0, stream>>>(gbuf, bcnt, bbase, offs, ssrc);
    // agg1 -> A1 cols 0:128
    k_agg<<<nb_w, 256, 0, stream>>>(A1, offs, ssrc);
    // h = relu(A1 @ B1 + b1) -> Hb
    k_gemm_bf<true><<<dim3(mblocks, 2), 256, 0, stream>>>(A1, B1t, b1, Hb);
    // [p|r] = Hb @ B2 -> Pb
    k_gemm_bf<false><<<dim3(mblocks, 2), 256, 0, stream>>>(Hb, B2t, nullptr, Pb);
    // out = log_softmax(mean_agg(p) + r + b2)
    k_final<<<nb_w, 256, 0, stream>>>(Pb, offs, ssrc, b2, out);
}